// Round 10
// baseline (116.178 us; speedup 1.0000x reference)
//
#include <hip/hip_runtime.h>
#include <math.h>

#define Bq 16
#define Tq 81
#define Dq 128
#define Hq 8
#define BT (Bq*Tq)          // 1296
#define BTD (Bq*Tq*Dq)      // 165888 (out region 0)
#define PS 84               // padded s-stride of P row in LDS
// ws layout (ushorts): Qh f16 [b][h][t][d] at 0; Vh f16 [b][h][s][d] next;
// xh f16 [b][t][g8-swizzled d] next (written by k_qkv by==0 blocks).
#define QV_SZ   (BT*Hq*Dq)              // 1327104 elems

#define LSTR 136            // k_qkv LDS row stride (ushorts): 16B-aligned rows

typedef __attribute__((ext_vector_type(8))) short short8;
typedef __attribute__((ext_vector_type(4))) float f32x4;
typedef _Float16 h2 __attribute__((ext_vector_type(2)));

__device__ __forceinline__ int imin(int a, int b) { return a < b ? a : b; }
__device__ __forceinline__ unsigned short f2bf(float f) {   // RNE f32 -> bf16
    unsigned u = __float_as_uint(f);
    u += 0x7fffu + ((u >> 16) & 1u);
    return (unsigned short)(u >> 16);
}
__device__ __forceinline__ unsigned short f2h(float f) {    // f32 -> f16 (RNE)
    _Float16 h = (_Float16)f;
    return *(unsigned short*)&h;
}
__device__ __forceinline__ unsigned pk2h(float a, float b) {  // 2xf32 -> packed f16
    h2 v; v[0] = (_Float16)a; v[1] = (_Float16)b;
    return *(unsigned*)&v;
}
// l1 step on 2 elems: d = q - x*w (v_pk_fma), |d| (v_and), f32 acc (v_dot2)
__device__ __forceinline__ float l1h(unsigned qv, unsigned xv, unsigned wv, float acc) {
    const h2 q = *(const h2*)&qv, xx = *(const h2*)&xv, ww = *(const h2*)&wv;
    h2 d = q - xx * ww;
    unsigned du = (*(unsigned*)&d) & 0x7fff7fffu;
    const h2 da = *(const h2*)&du;
#if __has_builtin(__builtin_amdgcn_fdot2)
    return __builtin_amdgcn_fdot2(da, (h2){(_Float16)1.f, (_Float16)1.f}, acc, false);
#else
    return acc + (float)da[0] + (float)da[1];
#endif
}
// f32 += dot2(packed f16 a, packed f16 b)
__device__ __forceinline__ float fdot2u(unsigned a, unsigned b, float c) {
#if __has_builtin(__builtin_amdgcn_fdot2)
    return __builtin_amdgcn_fdot2(*(const h2*)&a, *(const h2*)&b, c, false);
#else
    const h2 x = *(const h2*)&a, y = *(const h2*)&b;
    return c + (float)x[0] * (float)y[0] + (float)x[1] * (float)y[1];
#endif
}

// ---------------------------------------------------------------------------
// K1: QKV GEMM via bf16 MFMA 16x16x32. grid (21, 32), 256 thr = 4 waves.
// R9 (rerun; R9's bench was a GPU-acquisition timeout, kernel never ran):
// Q and V both stored as f16 (Q was f32 -> same value after the f16
// convert k_attn did anyway; V was bf16 -> f16 is MORE precise). Halves the
// Q write and k_attn's Q read. xh emission (by==0) unchanged from R8.
// ---------------------------------------------------------------------------
__global__ __launch_bounds__(256) void k_qkv_mfma(
    const float* __restrict__ x, const float* __restrict__ wqkv,
    const float* __restrict__ bias, const float* __restrict__ he,
    unsigned short* __restrict__ Qh, unsigned short* __restrict__ Vh,
    unsigned short* __restrict__ xh)
{
    __shared__ unsigned short xs[64 * LSTR];    // 17.4 KB
    __shared__ unsigned short wsh[64 * LSTR];   // 17.4 KB
    const int tid = threadIdx.x;
    const int w = tid >> 6, lane = tid & 63;
    const int ln = lane & 15, quad = lane >> 4;
    const int r0 = blockIdx.x * 64;               // m-row base (bx 0..20)
    const int n0 = blockIdx.y * 64;               // W-row base
    const int h  = blockIdx.y >> 2;
    const int isV = (blockIdx.y >> 1) & 1;
    const int c0 = (blockIdx.y & 1) * 64;

    #pragma unroll
    for (int i = 0; i < 8; ++i) {
        const int idx = tid + i * 256;            // 0..2047
        const int r = idx >> 5, c4 = idx & 31;
        const int gr = imin(r0 + r, BT - 1);      // clamp tail rows
        const float4 v = *(const float4*)(x + (size_t)gr * Dq + c4 * 4);
        ushort4 o;
        o.x = f2bf(v.x); o.y = f2bf(v.y); o.z = f2bf(v.z); o.w = f2bf(v.w);
        *(ushort4*)(&xs[r * LSTR + c4 * 4]) = o;

        const float4 vw = *(const float4*)(wqkv + (size_t)(n0 + r) * Dq + c4 * 4);
        ushort4 ow;
        ow.x = f2bf(vw.x); ow.y = f2bf(vw.y); ow.z = f2bf(vw.z); ow.w = f2bf(vw.w);
        *(ushort4*)(&wsh[r * LSTR + c4 * 4]) = ow;
    }

    // f16 swizzled x copy for k_attn_out (rows r0..r0+63), by==0 only
    if (blockIdx.y == 0) {
        #pragma unroll
        for (int i = 0; i < 4; ++i) {
            const int idx = tid + i * 256;        // 0..1023
            const int r = idx >> 4, g8 = idx & 15;
            const int gm = r0 + r;
            if (gm < BT) {
                const int bb = gm / 81, tt = gm - bb * 81;
                const float* src = x + (size_t)gm * Dq + g8 * 8;
                const float4 a = *(const float4*)(src);
                const float4 c = *(const float4*)(src + 4);
                uint4 o;
                o.x = pk2h(a.x, a.y); o.y = pk2h(a.z, a.w);
                o.z = pk2h(c.x, c.y); o.w = pk2h(c.z, c.w);
                *(uint4*)(&xh[((size_t)(bb * Tq + tt)) * Dq +
                              ((g8 ^ (tt & 7)) << 3)]) = o;
            }
        }
    }
    __syncthreads();

    const unsigned short* xa = xs + (w * 16 + ln) * LSTR + quad * 8;
    const unsigned short* wb = wsh + ln * LSTR + quad * 8;

    f32x4 acc[4];
    #pragma unroll
    for (int i = 0; i < 4; ++i) acc[i] = (f32x4){0.f, 0.f, 0.f, 0.f};

    #pragma unroll
    for (int kb = 0; kb < Dq; kb += 32) {
        const short8 af = *(const short8*)(xa + kb);
        #pragma unroll
        for (int nt = 0; nt < 4; ++nt) {
            const short8 bf = *(const short8*)(wb + nt * 16 * LSTR + kb);
            acc[nt] = __builtin_amdgcn_mfma_f32_16x16x32_bf16(af, bf, acc[nt], 0, 0, 0);
        }
    }

    const float scale = isV ? he[h] : 1.0f;
    unsigned short* const dst = isV ? Vh : Qh;
    const int gm0 = r0 + w * 16 + quad * 4;
    #pragma unroll
    for (int nt = 0; nt < 4; ++nt) {
        const float bn = bias[n0 + nt * 16 + ln];
        #pragma unroll
        for (int r = 0; r < 4; ++r) {
            const int gm = gm0 + r;
            if (gm < BT) {
                const int bb = gm / 81, tt = gm - bb * 81;
                const size_t o =
                    (((size_t)bb * Hq + h) * Tq + tt) * Dq + c0 + nt * 16 + ln;
                dst[o] = f2h((acc[nt][r] + bn) * scale);
            }
        }
    }
}

// ---------------------------------------------------------------------------
// K23: scores + softmax (+ap) + PV + gelu + fanout + residual.
// grid (81, 16) = (t, b), block 512 = 8 waves; wave = head.
// R9 changes vs R8 (post-mortem: R8 bundle neutral within noise; the one
// locatable VALU block left is scalar PV):
//  - V is f16 -> phase D uses v_dot2_f32_f16 on s-pairs: P packed to f16
//    pairs in LDS (phase C), V pairs built with 2 v_perm_b32 per 2s.
//    VALU per 2 elems: 4 -> 2 (halves D's VALU, the largest block left).
//  - Qh is f16 at source: Qlh staging is a raw uint4 copy (no cvt, half
//    the bytes).
// ---------------------------------------------------------------------------
__global__ __launch_bounds__(512) void k_attn_out(
    const float* __restrict__ x, const unsigned short* __restrict__ Qh,
    const float* __restrict__ wk, const float* __restrict__ msk,
    const unsigned short* __restrict__ Vh, const unsigned short* __restrict__ xh,
    const float* __restrict__ fw, const float* __restrict__ fb,
    float* __restrict__ out)
{
    __shared__ unsigned short xlh[Tq * Dq];   // 20.7 KB f16, granule-swizzled
    __shared__ unsigned short Qlh[Hq * Dq];   // 2 KB f16
    __shared__ unsigned short wklh[Hq * Dq];  // 2 KB f16
    __shared__ float Pl[Hq][PS];              // 2.7 KB
    __shared__ unsigned Plh[Hq][44];          // 1.4 KB f16 s-pairs (41 used)
    __shared__ float bo[Hq * Dq];             // 4 KB
    __shared__ float zs[Dq];                  // 0.5 KB

    const int tid = threadIdx.x;
    const int t0 = blockIdx.x, b = blockIdx.y;
    const int w = tid >> 6, lane = tid & 63;   // w = head

    // ---- Phase A: copy xh[b] -> xlh; copy Q row; cvt wk ----
    {
        const uint4* src = (const uint4*)(xh + (size_t)b * Tq * Dq);
        uint4* dst = (uint4*)xlh;
        for (int idx = tid; idx < Tq * 16; idx += 512)
            dst[idx] = src[idx];
    }
    if (tid < 128) {                                     // Q row t0, 8 heads
        const int hh = tid >> 4, g8 = tid & 15;
        *(uint4*)(&Qlh[hh * Dq + g8 * 8]) =
            *(const uint4*)(Qh + (((size_t)b * Hq + hh) * Tq + t0) * Dq + g8 * 8);
    }
    if (tid >= 256 && tid < 384) {                       // wk, 8 heads
        const int t2 = tid - 256;
        const int hh = t2 >> 4, g8 = t2 & 15;
        const float* src = wk + (size_t)hh * Dq + g8 * 8;
        const float4 a = *(const float4*)(src);
        const float4 c = *(const float4*)(src + 4);
        uint4 o;
        o.x = pk2h(a.x, a.y); o.y = pk2h(a.z, a.w);
        o.z = pk2h(c.x, c.y); o.w = pk2h(c.z, c.w);
        *(uint4*)(&wklh[hh * Dq + g8 * 8]) = o;
    }
    __syncthreads();

    // ---- Phase B: L1-distance scores, packed f16, f32 accumulate ----
    const unsigned short* wrow = wklh + w * Dq;
    const unsigned short* qrow = Qlh + w * Dq;
    const int sx = (lane & 7) << 3;           // (64+lane)&7 == lane&7
    float acc0 = 0.f, acc1 = 0.f;
    {   // main: s = lane
        const unsigned short* xrow = xlh + (size_t)lane * Dq;
        #pragma unroll 4
        for (int g8 = 0; g8 < 16; ++g8) {
            const uint4 kk = *(const uint4*)(xrow + ((g8 << 3) ^ sx));
            const uint4 wv = *(const uint4*)(wrow + (g8 << 3));
            const uint4 qq = *(const uint4*)(qrow + (g8 << 3));
            acc0 = l1h(qq.x, kk.x, wv.x, acc0);
            acc0 = l1h(qq.y, kk.y, wv.y, acc0);
            acc0 = l1h(qq.z, kk.z, wv.z, acc0);
            acc0 = l1h(qq.w, kk.w, wv.w, acc0);
        }
    }
    if (lane < Tq - 64) {   // tail: s = 64+lane on lanes 0..16 (softmax lanes)
        const unsigned short* xrow = xlh + (size_t)(64 + lane) * Dq;
        #pragma unroll 4
        for (int g8 = 0; g8 < 16; ++g8) {
            const uint4 kk = *(const uint4*)(xrow + ((g8 << 3) ^ sx));
            const uint4 wv = *(const uint4*)(wrow + (g8 << 3));
            const uint4 qq = *(const uint4*)(qrow + (g8 << 3));
            acc1 = l1h(qq.x, kk.x, wv.x, acc1);
            acc1 = l1h(qq.y, kk.y, wv.y, acc1);
            acc1 = l1h(qq.z, kk.z, wv.z, acc1);
            acc1 = l1h(qq.w, kk.w, wv.w, acc1);
        }
    }

    // ---- Phase C: wave softmax + P->LDS (f32 + packed f16 pairs) + ap ----
    {
        const float ns = -0.08838834764831845f;   // -1/sqrt(128)
        const bool has1 = (lane < Tq - 64);
        const float v0 = acc0 * ns;
        const float v1 = has1 ? acc1 * ns : -1e30f;
        float m = fmaxf(v0, v1);
        #pragma unroll
        for (int off = 32; off > 0; off >>= 1)
            m = fmaxf(m, __shfl_xor(m, off));
        const float e0 = __expf(v0 - m);
        const float e1 = has1 ? __expf(v1 - m) : 0.f;
        float ssum = e0 + e1;
        #pragma unroll
        for (int off = 32; off > 0; off >>= 1)
            ssum += __shfl_xor(ssum, off);
        const float rinv = 1.0f / ssum;
        const float* mrow = msk + ((size_t)w * Tq + t0) * Tq;
        const float mv0 = mrow[lane];
        const float p0 = e0 * rinv * mv0;
        Pl[w][lane] = p0;
        if (b == 0)
            out[BTD + ((size_t)t0 * Tq + lane) * Hq + w] = p0 - 1.0f + mv0;
        if (has1) {
            const float mv1 = mrow[64 + lane];
            const float p1 = e1 * rinv * mv1;
            Pl[w][64 + lane] = p1;
            if (b == 0)
                out[BTD + ((size_t)t0 * Tq + 64 + lane) * Hq + w] = p1 - 1.0f + mv1;
        }
        if (lane < 3) Pl[w][81 + lane] = 0.f;     // zero pad (pair 40 hi)
        // pack s-pairs to f16 for dot2 PV (same wave: RAW via lgkmcnt)
        if (lane < 41) {
            const float2 pp = *(const float2*)(&Pl[w][2 * lane]);
            Plh[w][lane] = pk2h(pp.x, pp.y);
        }
    }
    // NO barrier: Pl/Plh[w] are wave-private; bo is not an overlay.

    // ---- Phase D: PV einsum, f16 V, v_dot2 on s-pairs ----
    {
        const int d0 = lane * 2;
        float2 acc = make_float2(0.f, 0.f);
        const unsigned short* vp = Vh + (((size_t)b * Hq + w) * Tq) * Dq + d0;
        #pragma unroll 4
        for (int i = 0; i < 41; ++i) {
            // rows 2i and 2i+1 (i=40: row 81 overruns into xh region --
            // allocated, finite; killed by p-pair hi = 0)
            const unsigned u0 = *(const unsigned*)(vp + (size_t)(2 * i) * Dq);
            const unsigned u1 = *(const unsigned*)(vp + (size_t)(2 * i + 1) * Dq);
            const unsigned pp = Plh[w][i];
            const unsigned bx = __builtin_amdgcn_perm(u1, u0, 0x05040100u);
            const unsigned by = __builtin_amdgcn_perm(u1, u0, 0x07060302u);
            acc.x = fdot2u(pp, bx, acc.x);
            acc.y = fdot2u(pp, by, acc.y);
        }
        bo[w * Dq + d0]     = acc.x;
        bo[w * Dq + d0 + 1] = acc.y;
    }
    __syncthreads();

    // ---- Phase E: 8-way head reduce + quick-gelu (128 threads) ----
    if (tid < Dq) {
        float s = 0.f;
        #pragma unroll
        for (int ww = 0; ww < 8; ++ww) s += bo[ww * Dq + tid];
        const float tt2 = s + 4.0f;
        const float sg = 1.0f / (1.0f + __expf(-1.702f * tt2));
        zs[tid] = tt2 * sg - 4.0f;
    }
    __syncthreads();

    // ---- Phase F: fanout split-k x4 (4 threads per n, shfl reduce) ----
    {
        const int n = tid >> 2, kq = tid & 3;
        const float* fwr = fw + (size_t)n * Dq + kq * 32;
        float a0 = 0.f;
        #pragma unroll
        for (int k4 = 0; k4 < 8; ++k4) {
            const float4 w4 = *(const float4*)(fwr + k4 * 4);
            const float4 z0 = *(const float4*)(&zs[kq * 32 + k4 * 4]);
            a0 += z0.x * w4.x + z0.y * w4.y + z0.z * w4.z + z0.w * w4.w;
        }
        a0 += __shfl_xor(a0, 1);
        a0 += __shfl_xor(a0, 2);
        if (kq == 0) {
            const size_t o = ((size_t)b * Tq + t0) * Dq + n;
            out[o] = x[o] + a0 + fb[n];
        }
    }
}

extern "C" void kernel_launch(void* const* d_in, const int* in_sizes, int n_in,
                              void* d_out, int out_size, void* d_ws, size_t ws_size,
                              hipStream_t stream) {
    const float* x        = (const float*)d_in[0];
    const float* msk      = (const float*)d_in[1];
    const float* wqkv_w   = (const float*)d_in[2];
    const float* wqkv_b   = (const float*)d_in[3];
    const float* wk_w     = (const float*)d_in[4];
    const float* fanout_w = (const float*)d_in[5];
    const float* fanout_b = (const float*)d_in[6];
    const float* he       = (const float*)d_in[7];
    float* out = (float*)d_out;

    unsigned short* Qh = (unsigned short*)d_ws;
    unsigned short* Vh = Qh + (size_t)QV_SZ;
    unsigned short* xh = Vh + (size_t)QV_SZ;

    k_qkv_mfma<<<dim3(21, 32), 256, 0, stream>>>(x, wqkv_w, wqkv_b, he, Qh, Vh, xh);
    k_attn_out<<<dim3(Tq, 16), 512, 0, stream>>>(x, Qh, wk_w, msk, Vh, xh,
                                                 fanout_w, fanout_b, out);
}

// Round 11
// 111.760 us; speedup vs baseline: 1.0395x; 1.0395x over previous
//
#include <hip/hip_runtime.h>
#include <math.h>

#define Bq 16
#define Tq 81
#define Dq 128
#define Hq 8
#define BT (Bq*Tq)          // 1296
#define BTD (Bq*Tq*Dq)      // 165888 (out region 0)
#define PS 84               // padded s-stride of P row in LDS
// ws layout (floats). Q: [b][h][t][d] f32; V: [b][h][s][d] bf16 in V_OFF.
#define P_SZ   (Bq*Tq*Hq*PS)
#define QV_SZ  (BT*Hq*Dq)
#define P_OFF  0
#define Q_OFF  (P_OFF + P_SZ)
#define V_OFF  (Q_OFF + QV_SZ)

#define LSTR 136            // k_qkv LDS row stride (ushorts): 16B-aligned rows

typedef __attribute__((ext_vector_type(8))) short short8;
typedef __attribute__((ext_vector_type(4))) float f32x4;
typedef _Float16 h2 __attribute__((ext_vector_type(2)));

__device__ __forceinline__ int imin(int a, int b) { return a < b ? a : b; }
__device__ __forceinline__ unsigned short f2bf(float f) {   // RNE f32 -> bf16
    unsigned u = __float_as_uint(f);
    u += 0x7fffu + ((u >> 16) & 1u);
    return (unsigned short)(u >> 16);
}
__device__ __forceinline__ float bf2f(unsigned short s) {
    return __uint_as_float((unsigned)s << 16);
}
__device__ __forceinline__ unsigned pk2h(float a, float b) {  // 2xf32 -> packed f16
    h2 v; v[0] = (_Float16)a; v[1] = (_Float16)b;
    return *(unsigned*)&v;
}
// l1 step on 2 elems: d = q - x*w (v_pk_fma), |d| (v_and), f32 acc (v_dot2)
__device__ __forceinline__ float l1h(unsigned qv, unsigned xv, unsigned wv, float acc) {
    const h2 q = *(const h2*)&qv, xx = *(const h2*)&xv, ww = *(const h2*)&wv;
    h2 d = q - xx * ww;
    unsigned du = (*(unsigned*)&d) & 0x7fff7fffu;
    const h2 da = *(const h2*)&du;
#if __has_builtin(__builtin_amdgcn_fdot2)
    return __builtin_amdgcn_fdot2(da, (h2){(_Float16)1.f, (_Float16)1.f}, acc, false);
#else
    return acc + (float)da[0] + (float)da[1];
#endif
}

// ---------------------------------------------------------------------------
// K1: QKV GEMM via bf16 MFMA 16x16x32. grid (21, 32), 256 thr = 4 waves.
// Unchanged (verified).
// ---------------------------------------------------------------------------
__global__ __launch_bounds__(256) void k_qkv_mfma(
    const float* __restrict__ x, const float* __restrict__ wqkv,
    const float* __restrict__ bias, const float* __restrict__ he,
    float* __restrict__ Qo, unsigned short* __restrict__ Vb)
{
    __shared__ unsigned short xs[64 * LSTR];    // 17.4 KB
    __shared__ unsigned short wsh[64 * LSTR];   // 17.4 KB
    const int tid = threadIdx.x;
    const int w = tid >> 6, lane = tid & 63;
    const int ln = lane & 15, quad = lane >> 4;
    const int r0 = blockIdx.x * 64;               // m-row base (bx 0..20)
    const int n0 = blockIdx.y * 64;               // W-row base
    const int h  = blockIdx.y >> 2;
    const int isV = (blockIdx.y >> 1) & 1;
    const int c0 = (blockIdx.y & 1) * 64;

    #pragma unroll
    for (int i = 0; i < 8; ++i) {
        const int idx = tid + i * 256;            // 0..2047
        const int r = idx >> 5, c4 = idx & 31;
        const int gr = imin(r0 + r, BT - 1);      // clamp tail rows
        const float4 v = *(const float4*)(x + (size_t)gr * Dq + c4 * 4);
        ushort4 o;
        o.x = f2bf(v.x); o.y = f2bf(v.y); o.z = f2bf(v.z); o.w = f2bf(v.w);
        *(ushort4*)(&xs[r * LSTR + c4 * 4]) = o;

        const float4 vw = *(const float4*)(wqkv + (size_t)(n0 + r) * Dq + c4 * 4);
        ushort4 ow;
        ow.x = f2bf(vw.x); ow.y = f2bf(vw.y); ow.z = f2bf(vw.z); ow.w = f2bf(vw.w);
        *(ushort4*)(&wsh[r * LSTR + c4 * 4]) = ow;
    }
    __syncthreads();

    const unsigned short* xa = xs + (w * 16 + ln) * LSTR + quad * 8;
    const unsigned short* wb = wsh + ln * LSTR + quad * 8;

    f32x4 acc[4];
    #pragma unroll
    for (int i = 0; i < 4; ++i) acc[i] = (f32x4){0.f, 0.f, 0.f, 0.f};

    #pragma unroll
    for (int kb = 0; kb < Dq; kb += 32) {
        const short8 af = *(const short8*)(xa + kb);
        #pragma unroll
        for (int nt = 0; nt < 4; ++nt) {
            const short8 bf = *(const short8*)(wb + nt * 16 * LSTR + kb);
            acc[nt] = __builtin_amdgcn_mfma_f32_16x16x32_bf16(af, bf, acc[nt], 0, 0, 0);
        }
    }

    const float scale = isV ? he[h] : 1.0f;
    const int gm0 = r0 + w * 16 + quad * 4;
    #pragma unroll
    for (int nt = 0; nt < 4; ++nt) {
        const float bn = bias[n0 + nt * 16 + ln];
        #pragma unroll
        for (int r = 0; r < 4; ++r) {
            const int gm = gm0 + r;
            if (gm < BT) {
                const int bb = gm / 81, tt = gm - bb * 81;
                const size_t o =
                    (((size_t)bb * Hq + h) * Tq + tt) * Dq + c0 + nt * 16 + ln;
                const float val = (acc[nt][r] + bn) * scale;
                if (isV) Vb[o] = f2bf(val);
                else     Qo[o] = val;
            }
        }
    }
}

// ---------------------------------------------------------------------------
// K23: scores + softmax (+ap) + PV + gelu + fanout + residual.
// R11 = exact revert to the best-measured variant (R7, 111.5 us): the R8
// (xh pre-convert, barrier removal, split-k F) and R9 (f16 V dot2, f16 Q)
// bundles were cumulatively neutral-to-negative (111.5 -> 113.6 -> 116.2).
// grid (81, 16) = (t, b) = 1296 blocks, block 512 = 8 waves; wave = head.
//  - f16-packed scores: x/Q/wk staged as f16; per-2-elems the l1 core is
//    v_pk_fma_f16 (k=x*wk fused) + v_and (abs) + v_dot2_f32_f16 (f32 acc).
//  - tail s=64..80 owned by lanes 0..16 = the softmax has1 lanes -> tail
//    scores stay in registers.
// smem: xlh f16[81][128] swz (20.7 KB) | Qlh f16[8][128] | wklh f16[8][128]
//       | Pl f32[8][84]. Overlay after scores: bo[8][128] f32, zs[128] f32
//       on the xlh region.
// ---------------------------------------------------------------------------
__global__ __launch_bounds__(512) void k_attn_out(
    const float* __restrict__ x, const float* __restrict__ Q,
    const float* __restrict__ wk, const float* __restrict__ msk,
    const unsigned short* __restrict__ Vb, const float* __restrict__ fw,
    const float* __restrict__ fb, float* __restrict__ out)
{
    __shared__ unsigned short xlh[Tq * Dq];   // 20.7 KB f16, granule-swizzled
    __shared__ unsigned short Qlh[Hq * Dq];   // 2 KB f16
    __shared__ unsigned short wklh[Hq * Dq];  // 2 KB f16
    __shared__ float Pl[Hq][PS];              // 2.7 KB
    float* const bo = (float*)xlh;            // [8][128] overlay (D..E)
    float* const zs = (float*)xlh + 1024;     // [128]    overlay (E..F)

    const int tid = threadIdx.x;
    const int t0 = blockIdx.x, b = blockIdx.y;
    const int w = tid >> 6, lane = tid & 63;   // w = head

    // ---- Phase A: stage xlh (f16, 16B-granule XOR swizzle) + Qlh + wklh ----
    for (int idx = tid; idx < Tq * 16; idx += 512) {     // 1296 granules
        const int r = idx >> 4, g8 = idx & 15;
        const float* src = x + (size_t)(b * Tq + r) * Dq + g8 * 8;
        const float4 a = *(const float4*)(src);
        const float4 c = *(const float4*)(src + 4);
        uint4 o;
        o.x = pk2h(a.x, a.y); o.y = pk2h(a.z, a.w);
        o.z = pk2h(c.x, c.y); o.w = pk2h(c.z, c.w);
        *(uint4*)(&xlh[r * Dq + ((g8 ^ (r & 7)) << 3)]) = o;
    }
    if (tid < 128) {                                     // Q row t0, 8 heads
        const int hh = tid >> 4, g8 = tid & 15;
        const float* src = Q + (((size_t)b * Hq + hh) * Tq + t0) * Dq + g8 * 8;
        const float4 a = *(const float4*)(src);
        const float4 c = *(const float4*)(src + 4);
        uint4 o;
        o.x = pk2h(a.x, a.y); o.y = pk2h(a.z, a.w);
        o.z = pk2h(c.x, c.y); o.w = pk2h(c.z, c.w);
        *(uint4*)(&Qlh[hh * Dq + g8 * 8]) = o;
    }
    if (tid >= 256 && tid < 384) {                       // wk, 8 heads
        const int t2 = tid - 256;
        const int hh = t2 >> 4, g8 = t2 & 15;
        const float* src = wk + (size_t)hh * Dq + g8 * 8;
        const float4 a = *(const float4*)(src);
        const float4 c = *(const float4*)(src + 4);
        uint4 o;
        o.x = pk2h(a.x, a.y); o.y = pk2h(a.z, a.w);
        o.z = pk2h(c.x, c.y); o.w = pk2h(c.z, c.w);
        *(uint4*)(&wklh[hh * Dq + g8 * 8]) = o;
    }
    __syncthreads();

    // ---- Phase B: L1-distance scores, packed f16, f32 accumulate ----
    const unsigned short* wrow = wklh + w * Dq;
    const unsigned short* qrow = Qlh + w * Dq;
    const int sx = (lane & 7) << 3;           // (64+lane)&7 == lane&7
    float acc0 = 0.f, acc1 = 0.f;
    {   // main: s = lane
        const unsigned short* xrow = xlh + (size_t)lane * Dq;
        #pragma unroll 4
        for (int g8 = 0; g8 < 16; ++g8) {
            const uint4 kk = *(const uint4*)(xrow + ((g8 << 3) ^ sx));
            const uint4 wv = *(const uint4*)(wrow + (g8 << 3));
            const uint4 qq = *(const uint4*)(qrow + (g8 << 3));
            acc0 = l1h(qq.x, kk.x, wv.x, acc0);
            acc0 = l1h(qq.y, kk.y, wv.y, acc0);
            acc0 = l1h(qq.z, kk.z, wv.z, acc0);
            acc0 = l1h(qq.w, kk.w, wv.w, acc0);
        }
    }
    if (lane < Tq - 64) {   // tail: s = 64+lane on lanes 0..16 (softmax lanes)
        const unsigned short* xrow = xlh + (size_t)(64 + lane) * Dq;
        #pragma unroll 4
        for (int g8 = 0; g8 < 16; ++g8) {
            const uint4 kk = *(const uint4*)(xrow + ((g8 << 3) ^ sx));
            const uint4 wv = *(const uint4*)(wrow + (g8 << 3));
            const uint4 qq = *(const uint4*)(qrow + (g8 << 3));
            acc1 = l1h(qq.x, kk.x, wv.x, acc1);
            acc1 = l1h(qq.y, kk.y, wv.y, acc1);
            acc1 = l1h(qq.z, kk.z, wv.z, acc1);
            acc1 = l1h(qq.w, kk.w, wv.w, acc1);
        }
    }

    // ---- Phase C: wave softmax + P->LDS + fused ap (b==0) ----
    {
        const float ns = -0.08838834764831845f;   // -1/sqrt(128)
        const bool has1 = (lane < Tq - 64);
        const float v0 = acc0 * ns;
        const float v1 = has1 ? acc1 * ns : -1e30f;
        float m = fmaxf(v0, v1);
        #pragma unroll
        for (int off = 32; off > 0; off >>= 1)
            m = fmaxf(m, __shfl_xor(m, off));
        const float e0 = __expf(v0 - m);
        const float e1 = has1 ? __expf(v1 - m) : 0.f;
        float ssum = e0 + e1;
        #pragma unroll
        for (int off = 32; off > 0; off >>= 1)
            ssum += __shfl_xor(ssum, off);
        const float rinv = 1.0f / ssum;
        const float* mrow = msk + ((size_t)w * Tq + t0) * Tq;
        const float mv0 = mrow[lane];
        const float p0 = e0 * rinv * mv0;
        Pl[w][lane] = p0;
        if (b == 0)
            out[BTD + ((size_t)t0 * Tq + lane) * Hq + w] = p0 - 1.0f + mv0;
        if (has1) {
            const float mv1 = mrow[64 + lane];
            const float p1 = e1 * rinv * mv1;
            Pl[w][64 + lane] = p1;
            if (b == 0)
                out[BTD + ((size_t)t0 * Tq + 64 + lane) * Hq + w] = p1 - 1.0f + mv1;
        }
        if (lane < 3) Pl[w][81 + lane] = 0.f;     // zero pad (unused by D tail)
    }
    __syncthreads();   // all waves done reading xlh before bo overlay

    // ---- Phase D: PV einsum, bf16 V, s blocked by 4 ----
    {
        const int d0 = lane * 2;
        float2 acc = make_float2(0.f, 0.f);
        const unsigned short* vp = Vb + (((size_t)b * Hq + w) * Tq) * Dq + d0;
        for (int s4 = 0; s4 < 20; ++s4) {
            const float4 p = *(const float4*)(&Pl[w][s4 * 4]);
            #pragma unroll
            for (int ss = 0; ss < 4; ++ss) {
                const int s = s4 * 4 + ss;
                const ushort2 uv = *(const ushort2*)(vp + (size_t)s * Dq);
                const float pv = ((const float*)&p)[ss];
                acc.x = fmaf(pv, bf2f(uv.x), acc.x);
                acc.y = fmaf(pv, bf2f(uv.y), acc.y);
            }
        }
        {   // tail s = 80
            const ushort2 uv = *(const ushort2*)(vp + (size_t)80 * Dq);
            const float pv = Pl[w][80];
            acc.x = fmaf(pv, bf2f(uv.x), acc.x);
            acc.y = fmaf(pv, bf2f(uv.y), acc.y);
        }
        bo[w * Dq + d0]     = acc.x;
        bo[w * Dq + d0 + 1] = acc.y;
    }
    __syncthreads();

    // ---- Phase E: 8-way head reduce + quick-gelu (128 threads) ----
    if (tid < Dq) {
        float s = 0.f;
        #pragma unroll
        for (int ww = 0; ww < 8; ++ww) s += bo[ww * Dq + tid];
        const float tt2 = s + 4.0f;
        const float sg = 1.0f / (1.0f + __expf(-1.702f * tt2));
        zs[tid] = tt2 * sg - 4.0f;
    }
    __syncthreads();

    // ---- Phase F: fanout + bias + residual (128 threads, 1 n each) ----
    if (tid < Dq) {
        const int n = tid;
        const float* fwr = fw + (size_t)n * Dq;
        float a0 = 0.f;
        #pragma unroll 8
        for (int k4 = 0; k4 < 32; ++k4) {
            const float4 w4 = *(const float4*)(fwr + k4 * 4);
            const float4 z0 = *(const float4*)(&zs[k4 * 4]);
            a0 += z0.x * w4.x + z0.y * w4.y + z0.z * w4.z + z0.w * w4.w;
        }
        const size_t o = ((size_t)b * Tq + t0) * Dq + n;
        out[o] = x[o] + a0 + fb[n];
    }
}

extern "C" void kernel_launch(void* const* d_in, const int* in_sizes, int n_in,
                              void* d_out, int out_size, void* d_ws, size_t ws_size,
                              hipStream_t stream) {
    const float* x        = (const float*)d_in[0];
    const float* msk      = (const float*)d_in[1];
    const float* wqkv_w   = (const float*)d_in[2];
    const float* wqkv_b   = (const float*)d_in[3];
    const float* wk_w     = (const float*)d_in[4];
    const float* fanout_w = (const float*)d_in[5];
    const float* fanout_b = (const float*)d_in[6];
    const float* he       = (const float*)d_in[7];
    float* out = (float*)d_out;
    float* ws  = (float*)d_ws;

    float* Q  = ws + Q_OFF;
    unsigned short* Vb = (unsigned short*)(ws + V_OFF);

    k_qkv_mfma<<<dim3(21, 32), 256, 0, stream>>>(x, wqkv_w, wqkv_b, he, Q, Vb);
    k_attn_out<<<dim3(Tq, 16), 512, 0, stream>>>(x, Q, wk_w, msk, Vb,
                                                 fanout_w, fanout_b, out);
}